// Round 1
// baseline (619.777 us; speedup 1.0000x reference)
//
#include <hip/hip_runtime.h>
#include <math.h>

// Problem constants (from reference)
static constexpr int Zc  = 64;    // z_dim
static constexpr int Xc  = 32;    // x_dim
static constexpr int THc = 128;   // trans_hidden
static constexpr int OHc = 64;    // obs_hidden
static constexpr int Bc  = 4096;  // batch
static constexpr int Tc  = 256;   // time

__device__ __forceinline__ float sig_(float x) { return 1.0f / (1.0f + expf(-x)); }

// dot of per-thread register row w[64] with a 64-float LDS vector (broadcast reads)
__device__ __forceinline__ float dot64(const float* w, const float* x) {
  float a0 = 0.f, a1 = 0.f, a2 = 0.f, a3 = 0.f;
#pragma unroll
  for (int k = 0; k < 16; ++k) {
    float4 v = ((const float4*)x)[k];
    a0 = fmaf(w[4 * k + 0], v.x, a0);
    a1 = fmaf(w[4 * k + 1], v.y, a1);
    a2 = fmaf(w[4 * k + 2], v.z, a2);
    a3 = fmaf(w[4 * k + 3], v.w, a3);
  }
  return (a0 + a1) + (a2 + a3);
}

// Serial recurrence, 1 block x 512 threads. Weights live in per-thread registers.
// Observation head executes pipelined one step behind in otherwise-idle phases.
// x rows are written to out[0, t, 0:64] (the b=0 slice IS the broadcast table).
__global__ __launch_bounds__(512) void chain_kernel(
    const float* __restrict__ z0, const float* __restrict__ h0,
    const float* __restrict__ W_ih, const float* __restrict__ W_hh,
    const float* __restrict__ b_ih, const float* __restrict__ b_hh,
    const float* __restrict__ W_gzh, const float* __restrict__ b_gzh,
    const float* __restrict__ W_ghz, const float* __restrict__ b_ghz,
    const float* __restrict__ W_pzh, const float* __restrict__ b_pzh,
    const float* __restrict__ W_phz, const float* __restrict__ b_phz,
    const float* __restrict__ W_zloc, const float* __restrict__ b_zloc,
    const float* __restrict__ W_olh, const float* __restrict__ b_olh,
    const float* __restrict__ W_olx, const float* __restrict__ b_olx,
    const float* __restrict__ W_osh, const float* __restrict__ b_osh,
    const float* __restrict__ W_osx, const float* __restrict__ b_osx,
    float* __restrict__ out) {
  const int tid = threadIdx.x;

  __shared__ __align__(16) float zbuf[64];    // z_{t}
  __shared__ __align__(16) float hbuf[64];    // rnn_out_{t}
  __shared__ __align__(16) float gibuf[192];  // W_ih z + b_ih
  __shared__ __align__(16) float ghbuf[192];  // W_hh h + b_hh
  __shared__ __align__(16) float abuf[128];   // relu(gzh hidden)
  __shared__ __align__(16) float cbuf[128];   // relu(pzh hidden)
  __shared__ __align__(16) float gatebuf[64];
  __shared__ __align__(16) float pmbuf[64];
  __shared__ __align__(16) float olbuf[64];   // relu(olh hidden), step t-1
  __shared__ __align__(16) float osbuf[64];   // relu(osh hidden), step t-1

  // ---- per-thread register weight rows (uniform layout across all threads) ----
  float wP1[64], wP3[64], wP4[64];
  float bP1 = 0.f, bP3 = 0.f, bP4 = 0.f;

  // wP1: phase-A rows.
  //   tid 0-191   : W_ih row tid          (GRU input gates)
  //   tid 192-383 : W_hh row tid-192      (GRU hidden gates)
  //   tid 384-447 : W_olh row tid-384     (obs loc hidden, pipelined)
  //   tid 448-511 : W_osh row tid-448     (obs scale hidden, pipelined)
  {
    const float* p;
    if (tid < 192)      { p = W_ih  + tid * 64;         bP1 = b_ih[tid]; }
    else if (tid < 384) { p = W_hh  + (tid - 192) * 64; bP1 = b_hh[tid - 192]; }
    else if (tid < 448) { p = W_olh + (tid - 384) * 64; bP1 = b_olh[tid - 384]; }
    else                { p = W_osh + (tid - 448) * 64; bP1 = b_osh[tid - 448]; }
#pragma unroll
    for (int k = 0; k < 16; ++k) {
      float4 v = ((const float4*)p)[k];
      wP1[4 * k + 0] = v.x; wP1[4 * k + 1] = v.y;
      wP1[4 * k + 2] = v.z; wP1[4 * k + 3] = v.w;
    }
  }

  // wP3: phase-C rows.
  //   tid 0-127   : W_gzh row tid
  //   tid 128-255 : W_pzh row tid-128
  //   tid 256-319 : W_zloc row tid-256
  //   tid 320-351 : W_olx row tid-320    (obs final, pipelined)
  //   tid 352-383 : W_osx row tid-352    (obs final, pipelined)
  //   tid 384-511 : unused (dummy load)
  {
    const float* p;
    if (tid < 128)      { p = W_gzh  + tid * 64;         bP3 = b_gzh[tid]; }
    else if (tid < 256) { p = W_pzh  + (tid - 128) * 64; bP3 = b_pzh[tid - 128]; }
    else if (tid < 320) { p = W_zloc + (tid - 256) * 64; bP3 = b_zloc[tid - 256]; }
    else if (tid < 352) { p = W_olx  + (tid - 320) * 64; bP3 = b_olx[tid - 320]; }
    else if (tid < 384) { p = W_osx  + (tid - 352) * 64; bP3 = b_osx[tid - 352]; }
    else                { p = W_gzh; }
#pragma unroll
    for (int k = 0; k < 16; ++k) {
      float4 v = ((const float4*)p)[k];
      wP3[4 * k + 0] = v.x; wP3[4 * k + 1] = v.y;
      wP3[4 * k + 2] = v.z; wP3[4 * k + 3] = v.w;
    }
  }

  // wP4: phase-D half-rows (K=128 split across lane pairs l <-> l^32 of one wave).
  //   wave 4 (tid 256-319): gate rows  0-31, wave 5: gate rows 32-63  (W_ghz)
  //   wave 6 (tid 384-447): pm   rows  0-31, wave 7: pm   rows 32-63  (W_phz)
  {
    const float* p = W_ghz;  // dummy for tid<256
    if (tid >= 256) {
      int wv = tid >> 6;        // 4..7
      int lane = tid & 63;
      int row = (lane & 31) + (((wv & 1) != 0) ? 32 : 0);
      int half = lane >> 5;
      if (wv < 6) { p = W_ghz + row * 128 + half * 64; bP4 = b_ghz[row]; }
      else        { p = W_phz + row * 128 + half * 64; bP4 = b_phz[row]; }
    }
#pragma unroll
    for (int k = 0; k < 16; ++k) {
      float4 v = ((const float4*)p)[k];
      wP4[4 * k + 0] = v.x; wP4[4 * k + 1] = v.y;
      wP4[4 * k + 2] = v.z; wP4[4 * k + 3] = v.w;
    }
  }

  if (tid < 64) { zbuf[tid] = z0[tid]; hbuf[tid] = h0[tid]; }
  __syncthreads();

  float zlin_reg = 0.f;

  for (int t = 0; t <= Tc; ++t) {
    const bool step = (t < Tc);
    const bool obs  = (t >= 1);

    // ---- Phase A: GRU matvecs (chain, step t) || obs hidden (step t-1) ----
    if (step && tid < 384) {
      const float* x = (tid < 192) ? zbuf : hbuf;   // wave-uniform select
      float acc = dot64(wP1, x) + bP1;
      if (tid < 192) gibuf[tid] = acc; else ghbuf[tid - 192] = acc;
    }
    if (obs && tid >= 384) {
      float acc = dot64(wP1, zbuf) + bP1;           // zbuf holds z_{t-1}
      acc = fmaxf(acc, 0.f);
      if (tid < 448) olbuf[tid - 384] = acc; else osbuf[tid - 448] = acc;
    }
    __syncthreads();

    // ---- Phase B: GRU elementwise -> rnn_out ----
    if (step && tid < 64) {
      float ir = gibuf[tid], iu = gibuf[64 + tid], inn = gibuf[128 + tid];
      float hr = ghbuf[tid], hu = ghbuf[64 + tid], hn = ghbuf[128 + tid];
      float r = sig_(ir + hr);
      float u = sig_(iu + hu);
      float nn = tanhf(inn + r * hn);
      float hp = hbuf[tid];
      hbuf[tid] = (1.f - u) * nn + u * hp;
    }
    __syncthreads();

    // ---- Phase C: transition hiddens + z_lin (chain) || obs final (t-1) ----
    if (step && tid < 320) {
      float acc = dot64(wP3, hbuf) + bP3;
      if (tid < 256) {
        acc = fmaxf(acc, 0.f);
        if (tid < 128) abuf[tid] = acc; else cbuf[tid - 128] = acc;
      } else {
        zlin_reg = acc;                              // W_zloc rnn + b_zloc
      }
    }
    if (obs && tid >= 320 && tid < 384) {
      const float* x = (tid < 352) ? olbuf : osbuf;  // divergent halves ok
      float acc = dot64(wP3, x) + bP3;
      acc = fmaxf(acc, 0.f);
      out[(size_t)(t - 1) * 64 + (tid - 320)] = acc; // cols 0-31 loc, 32-63 scale
    }
    __syncthreads();

    // ---- Phase D: gate / proposed-mean (K=128, lane-pair split + shfl) ----
    if (step && tid >= 256) {
      int lane = tid & 63;
      int half = lane >> 5;
      const float* x = (tid < 384) ? (abuf + half * 64) : (cbuf + half * 64);
      float part = dot64(wP4, x);
      float tot = part + __shfl_xor(part, 32, 64);
      if (lane < 32) {
        int row = (lane & 31) + ((((tid >> 6) & 1) != 0) ? 32 : 0);
        if (tid < 384) gatebuf[row] = sig_(tot + bP4);
        else           pmbuf[row]   = tot + bP4;
      }
    }
    __syncthreads();

    // ---- Phase E: z_t = (1-gate)*z_lin + gate*pm ----
    if (step && tid >= 256 && tid < 320) {
      int j = tid - 256;
      float g = gatebuf[j];
      zbuf[j] = (1.f - g) * zlin_reg + g * pmbuf[j];
    }
    __syncthreads();
  }
}

// out[n] = out[n mod 16384] for n >= 16384; 16384 = T*2X is a power of two.
__global__ __launch_bounds__(256) void bcast_kernel(float* __restrict__ out) {
  const size_t total4 = (size_t)Bc * Tc * (2 * Xc) / 4;  // 16,777,216 float4
  const size_t src4   = (size_t)Tc * (2 * Xc) / 4;        // 4096 float4
  const float4* s = (const float4*)out;
  float4* o = (float4*)out;
  size_t stride = (size_t)gridDim.x * blockDim.x;
  for (size_t i = (size_t)blockIdx.x * blockDim.x + threadIdx.x + src4;
       i < total4; i += stride) {
    o[i] = s[i & (src4 - 1)];
  }
}

extern "C" void kernel_launch(void* const* d_in, const int* in_sizes, int n_in,
                              void* d_out, int out_size, void* d_ws, size_t ws_size,
                              hipStream_t stream) {
  (void)in_sizes; (void)n_in; (void)d_ws; (void)ws_size; (void)out_size;
  // setup_inputs order:
  // 0 mini_batch (unused!) 1 z0 2 h0 3 W_ih 4 W_hh 5 b_ih 6 b_hh
  // 7 W_gzh 8 b_gzh 9 W_ghz 10 b_ghz 11 W_pzh 12 b_pzh 13 W_phz 14 b_phz
  // 15 W_zloc 16 b_zloc 17 W_zscale(unused) 18 b_zscale(unused)
  // 19 W_olh 20 b_olh 21 W_olx 22 b_olx 23 W_osh 24 b_osh 25 W_osx 26 b_osx
  const float* z0     = (const float*)d_in[1];
  const float* h0     = (const float*)d_in[2];
  const float* W_ih   = (const float*)d_in[3];
  const float* W_hh   = (const float*)d_in[4];
  const float* b_ih   = (const float*)d_in[5];
  const float* b_hh   = (const float*)d_in[6];
  const float* W_gzh  = (const float*)d_in[7];
  const float* b_gzh  = (const float*)d_in[8];
  const float* W_ghz  = (const float*)d_in[9];
  const float* b_ghz  = (const float*)d_in[10];
  const float* W_pzh  = (const float*)d_in[11];
  const float* b_pzh  = (const float*)d_in[12];
  const float* W_phz  = (const float*)d_in[13];
  const float* b_phz  = (const float*)d_in[14];
  const float* W_zloc = (const float*)d_in[15];
  const float* b_zloc = (const float*)d_in[16];
  const float* W_olh  = (const float*)d_in[19];
  const float* b_olh  = (const float*)d_in[20];
  const float* W_olx  = (const float*)d_in[21];
  const float* b_olx  = (const float*)d_in[22];
  const float* W_osh  = (const float*)d_in[23];
  const float* b_osh  = (const float*)d_in[24];
  const float* W_osx  = (const float*)d_in[25];
  const float* b_osx  = (const float*)d_in[26];
  float* out = (float*)d_out;

  chain_kernel<<<1, 512, 0, stream>>>(
      z0, h0, W_ih, W_hh, b_ih, b_hh,
      W_gzh, b_gzh, W_ghz, b_ghz, W_pzh, b_pzh, W_phz, b_phz,
      W_zloc, b_zloc, W_olh, b_olh, W_olx, b_olx,
      W_osh, b_osh, W_osx, b_osx, out);

  bcast_kernel<<<2048, 256, 0, stream>>>(out);
}